// Round 6
// baseline (665.029 us; speedup 1.0000x reference)
//
#include <hip/hip_runtime.h>
#include <hip/hip_cooperative_groups.h>

namespace cg = cooperative_groups;

#define HDIM  128
#define FBLKS 1024        // cooperative grid: 4 blocks/CU x 256 CU, all co-resident
#define HBLKS (FBLKS / 2) // blocks per half (A / B) in the gemm phase

typedef __bf16 bf16_t;
typedef bf16_t bf16x8 __attribute__((ext_vector_type(8)));
typedef float  f32x4  __attribute__((ext_vector_type(4)));

__device__ __forceinline__ unsigned short f2bf_rne(float f) {
    unsigned int u = __float_as_uint(f);
    u += 0x7fffu + ((u >> 16) & 1u);   // round-to-nearest-even
    return (unsigned short)(u >> 16);
}
__device__ __forceinline__ unsigned int pk_bf2(float a, float b) {
    return (unsigned int)f2bf_rne(a) | ((unsigned int)f2bf_rne(b) << 16);
}

// W1 [2*128 k][128 n] fp32 -> Wt [2][n=128][k=128] bf16 (n-major, k-contiguous)
__global__ __launch_bounds__(256) void convert_w1(
    const float* __restrict__ W1, unsigned short* __restrict__ Wt)
{
    const int o = blockIdx.x * 256 + threadIdx.x;     // 0..32767
    const int g = o >> 14, rem = o & 16383, n = rem >> 7, k = rem & 127;
    Wt[o] = f2bf_rne(W1[g * 16384 + k * 128 + n]);
}

// ===== fused: node-gemm phase -> grid sync -> edge-decode phase ============
// Rationale: 5 rounds of gemm variants were total-level invariant while the
// gemm stayed below the top-5 counter cutoff. One fused kernel IS the
// slowest dispatch -> direct counter visibility; also removes 2 launches
// and their drain bubbles. Phase 1 = v6 gemm (best total), phase 2 = decode.
__global__ __launch_bounds__(256, 4) void fused_gemm_decode(
    const float* __restrict__ Zs, const float* __restrict__ Zd,
    const unsigned short* __restrict__ Wt, const float* __restrict__ b1,
    unsigned short* __restrict__ Abuf, unsigned short* __restrict__ Bbuf,
    const int* __restrict__ idx, const float* __restrict__ W2,
    const float* __restrict__ b2, float* __restrict__ out,
    int M, int E, int tiles_per_half)
{
    __shared__ unsigned short wlds[128 * 128];   // 32 KB

    const int t    = threadIdx.x;
    const int lane = t & 63;
    const int wave = t >> 6;
    const int m    = lane & 15;
    const int quad = lane >> 4;

    // ---------------- phase 1: C_bf16 = bf16(Z) @ bf16(W) (+ b1) ----------
    {
        const bool second = (blockIdx.x >= HBLKS);
        const int bx = second ? (blockIdx.x - HBLKS) : blockIdx.x;
        const float* __restrict__ Z          = second ? Zd : Zs;
        const unsigned short* __restrict__ W = Wt + (second ? 128 * 128 : 0);
        unsigned short* __restrict__ C       = second ? Bbuf : Abuf;

        // issue first tile's Z loads before staging (HBM latency hides under it)
        float4 zv[4][2];
        const bool has0 = (bx < tiles_per_half);
        if (has0) {
            const int r  = bx * 64 + wave * 16 + m;
            const int rc = (r < M) ? r : (M - 1);
            const float* zrow = Z + (size_t)rc * HDIM;
            #pragma unroll
            for (int ks = 0; ks < 4; ++ks) {
                zv[ks][0] = *reinterpret_cast<const float4*>(zrow + ks * 32 + quad * 8);
                zv[ks][1] = *reinterpret_cast<const float4*>(zrow + ks * 32 + quad * 8 + 4);
            }
        }

        // stage W once per block, XOR-swizzled 16B chunks (T2)
        #pragma unroll
        for (int j = 0; j < 8; ++j) {
            const int u = t + 256 * j;          // 0..2047
            const int n = u >> 4, cc = u & 15;
            const uint4 v = *reinterpret_cast<const uint4*>(W + n * 128 + cc * 8);
            *reinterpret_cast<uint4*>(wlds + n * 128 + (cc ^ (n & 7)) * 8) = v;
        }
        __syncthreads();

        for (int tile = bx; tile < tiles_per_half; tile += HBLKS) {
            const int r  = tile * 64 + wave * 16 + m;
            if (tile != bx) {                   // later tiles: load Z here
                const int rc = (r < M) ? r : (M - 1);
                const float* zrow = Z + (size_t)rc * HDIM;
                #pragma unroll
                for (int ks = 0; ks < 4; ++ks) {
                    zv[ks][0] = *reinterpret_cast<const float4*>(zrow + ks * 32 + quad * 8);
                    zv[ks][1] = *reinterpret_cast<const float4*>(zrow + ks * 32 + quad * 8 + 4);
                }
            }

            union { unsigned int u[4]; bf16x8 h; } zf[4];
            #pragma unroll
            for (int ks = 0; ks < 4; ++ks) {
                zf[ks].u[0] = pk_bf2(zv[ks][0].x, zv[ks][0].y);
                zf[ks].u[1] = pk_bf2(zv[ks][0].z, zv[ks][0].w);
                zf[ks].u[2] = pk_bf2(zv[ks][1].x, zv[ks][1].y);
                zf[ks].u[3] = pk_bf2(zv[ks][1].z, zv[ks][1].w);
            }

            f32x4 acc[8] = {};
            #pragma unroll
            for (int ks = 0; ks < 4; ++ks) {
                const int cidx = (ks * 4 + quad) ^ (m & 7);   // swizzled chunk
                #pragma unroll
                for (int ct = 0; ct < 8; ++ct) {
                    const bf16x8 wf = *reinterpret_cast<const bf16x8*>(
                        wlds + (ct * 16 + m) * 128 + cidx * 8);
                    acc[ct] = __builtin_amdgcn_mfma_f32_16x16x32_bf16(
                        wf, zf[ks].h, acc[ct], 0, 0, 0);
                }
            }

            if (r < M) {
                unsigned short* crow = C + (size_t)r * HDIM;
                #pragma unroll
                for (int ct = 0; ct < 8; ++ct) {
                    const int col = ct * 16 + quad * 4;
                    float4 bv = make_float4(0.f, 0.f, 0.f, 0.f);
                    if (second) bv = *reinterpret_cast<const float4*>(b1 + col);
                    uint2 o;
                    o.x = pk_bf2(acc[ct][0] + bv.x, acc[ct][1] + bv.y);
                    o.y = pk_bf2(acc[ct][2] + bv.z, acc[ct][3] + bv.w);
                    *reinterpret_cast<uint2*>(crow + col) = o;
                }
            }
        }
    }

    // device-scope visibility of Abuf/Bbuf across XCDs, then grid barrier
    __threadfence();
    cg::this_grid().sync();

    // ---------------- phase 2: out[e] = relu(A[r]+B[c]).W2 + b2 ------------
    {
        const int sub = t & 15;
        const int grp = t >> 4;

        float w2r[8];
        #pragma unroll
        for (int i = 0; i < 8; ++i) w2r[i] = W2[sub * 8 + i];
        const float b2s = b2[0];

        const int stride = FBLKS * 16;
        for (int e = blockIdx.x * 16 + grp; e < E; e += stride) {
            const int r = idx[e];
            const int c = idx[E + e];
            const uint4 av = *reinterpret_cast<const uint4*>(Abuf + (size_t)r * HDIM + sub * 8);
            const uint4 bv = *reinterpret_cast<const uint4*>(Bbuf + (size_t)c * HDIM + sub * 8);

            float s = 0.f;
            #pragma unroll
            for (int i = 0; i < 4; ++i) {
                const unsigned int ua = (&av.x)[i];
                const unsigned int ub = (&bv.x)[i];
                s += fmaxf(__uint_as_float(ua << 16)         + __uint_as_float(ub << 16),         0.f) * w2r[2 * i];
                s += fmaxf(__uint_as_float(ua & 0xffff0000u) + __uint_as_float(ub & 0xffff0000u), 0.f) * w2r[2 * i + 1];
            }
            s += __shfl_xor(s, 1);
            s += __shfl_xor(s, 2);
            s += __shfl_xor(s, 4);
            s += __shfl_xor(s, 8);
            if (sub == 0) out[e] = s + b2s;
        }
    }
}

// ===== fallback path (identical to R4) if cooperative launch unavailable ===
__global__ __launch_bounds__(256) void node_gemm_v6(
    const float* __restrict__ Zs, const float* __restrict__ Zd,
    const unsigned short* __restrict__ Wt, const float* __restrict__ b1,
    unsigned short* __restrict__ Abuf, unsigned short* __restrict__ Bbuf,
    int M, int tiles_per_half)
{
    __shared__ unsigned short wlds[128 * 128];

    const bool second = (blockIdx.x >= tiles_per_half);
    const int tile = second ? (blockIdx.x - tiles_per_half) : blockIdx.x;
    const float* __restrict__ Z          = second ? Zd : Zs;
    const unsigned short* __restrict__ W = Wt + (second ? 128 * 128 : 0);
    unsigned short* __restrict__ C       = second ? Bbuf : Abuf;
    const int t    = threadIdx.x;
    const int lane = t & 63;
    const int wave = t >> 6;
    const int m    = lane & 15;
    const int quad = lane >> 4;

    const int r  = tile * 64 + wave * 16 + m;
    const int rc = (r < M) ? r : (M - 1);
    const float* zrow = Z + (size_t)rc * HDIM;
    float4 zv[4][2];
    #pragma unroll
    for (int ks = 0; ks < 4; ++ks) {
        zv[ks][0] = *reinterpret_cast<const float4*>(zrow + ks * 32 + quad * 8);
        zv[ks][1] = *reinterpret_cast<const float4*>(zrow + ks * 32 + quad * 8 + 4);
    }

    #pragma unroll
    for (int j = 0; j < 8; ++j) {
        const int u = t + 256 * j;
        const int n = u >> 4, cc = u & 15;
        const uint4 v = *reinterpret_cast<const uint4*>(W + n * 128 + cc * 8);
        *reinterpret_cast<uint4*>(wlds + n * 128 + (cc ^ (n & 7)) * 8) = v;
    }
    __syncthreads();

    union { unsigned int u[4]; bf16x8 h; } zf[4];
    #pragma unroll
    for (int ks = 0; ks < 4; ++ks) {
        zf[ks].u[0] = pk_bf2(zv[ks][0].x, zv[ks][0].y);
        zf[ks].u[1] = pk_bf2(zv[ks][0].z, zv[ks][0].w);
        zf[ks].u[2] = pk_bf2(zv[ks][1].x, zv[ks][1].y);
        zf[ks].u[3] = pk_bf2(zv[ks][1].z, zv[ks][1].w);
    }

    f32x4 acc[8] = {};
    #pragma unroll
    for (int ks = 0; ks < 4; ++ks) {
        const int cidx = (ks * 4 + quad) ^ (m & 7);
        #pragma unroll
        for (int ct = 0; ct < 8; ++ct) {
            const bf16x8 wf = *reinterpret_cast<const bf16x8*>(
                wlds + (ct * 16 + m) * 128 + cidx * 8);
            acc[ct] = __builtin_amdgcn_mfma_f32_16x16x32_bf16(
                wf, zf[ks].h, acc[ct], 0, 0, 0);
        }
    }

    if (r < M) {
        unsigned short* crow = C + (size_t)r * HDIM;
        #pragma unroll
        for (int ct = 0; ct < 8; ++ct) {
            const int col = ct * 16 + quad * 4;
            float4 bv = make_float4(0.f, 0.f, 0.f, 0.f);
            if (second) bv = *reinterpret_cast<const float4*>(b1 + col);
            uint2 o;
            o.x = pk_bf2(acc[ct][0] + bv.x, acc[ct][1] + bv.y);
            o.y = pk_bf2(acc[ct][2] + bv.z, acc[ct][3] + bv.w);
            *reinterpret_cast<uint2*>(crow + col) = o;
        }
    }
}

__global__ __launch_bounds__(256) void edge_decode_bf16(
    const unsigned short* __restrict__ A, const unsigned short* __restrict__ Bm,
    const int* __restrict__ idx,
    const float* __restrict__ W2, const float* __restrict__ b2,
    float* __restrict__ out, int E)
{
    const int t   = threadIdx.x;
    const int sub = t & 15;
    const int grp = t >> 4;

    float w2r[8];
    #pragma unroll
    for (int i = 0; i < 8; ++i) w2r[i] = W2[sub * 8 + i];
    const float b2s = b2[0];

    const int stride = gridDim.x * 16;
    for (int e = blockIdx.x * 16 + grp; e < E; e += stride) {
        const int r = idx[e];
        const int c = idx[E + e];
        const uint4 av = *reinterpret_cast<const uint4*>(A  + (size_t)r * HDIM + sub * 8);
        const uint4 bv = *reinterpret_cast<const uint4*>(Bm + (size_t)c * HDIM + sub * 8);

        float s = 0.f;
        #pragma unroll
        for (int i = 0; i < 4; ++i) {
            const unsigned int ua = (&av.x)[i];
            const unsigned int ub = (&bv.x)[i];
            s += fmaxf(__uint_as_float(ua << 16)         + __uint_as_float(ub << 16),         0.f) * w2r[2 * i];
            s += fmaxf(__uint_as_float(ua & 0xffff0000u) + __uint_as_float(ub & 0xffff0000u), 0.f) * w2r[2 * i + 1];
        }
        s += __shfl_xor(s, 1);
        s += __shfl_xor(s, 2);
        s += __shfl_xor(s, 4);
        s += __shfl_xor(s, 8);
        if (sub == 0) out[e] = s + b2s;
    }
}

extern "C" void kernel_launch(void* const* d_in, const int* in_sizes, int n_in,
                              void* d_out, int out_size, void* d_ws, size_t ws_size,
                              hipStream_t stream)
{
    const float* z_src = (const float*)d_in[0];
    const float* z_dst = (const float*)d_in[1];
    const int*   eidx  = (const int*)d_in[2];
    const float* W1    = (const float*)d_in[3];
    const float* b1    = (const float*)d_in[4];
    const float* W2    = (const float*)d_in[5];
    const float* b2    = (const float*)d_in[6];
    float*       outp  = (float*)d_out;

    const int Nn = in_sizes[0] / HDIM;    // 100000
    const int E  = in_sizes[2] / 2;       // 2000000

    unsigned short* Abuf = (unsigned short*)d_ws;
    unsigned short* Bbuf = Abuf + (size_t)Nn * HDIM;
    unsigned short* Wt   = Bbuf + (size_t)Nn * HDIM;

    convert_w1<<<128, 256, 0, stream>>>(W1, Wt);

    const int tiles = (Nn + 63) >> 6;     // 1563

    // cooperative fused launch (1024 blocks, all co-resident)
    const float* Zs_ = z_src;  const float* Zd_ = z_dst;
    const unsigned short* Wt_ = Wt;  const float* b1_ = b1;
    unsigned short* A_ = Abuf; unsigned short* B_ = Bbuf;
    const int* idx_ = eidx;    const float* W2_ = W2; const float* b2_ = b2;
    float* out_ = outp;        int M_ = Nn; int E_ = E; int tl_ = tiles;
    void* args[] = { &Zs_, &Zd_, &Wt_, &b1_, &A_, &B_, &idx_, &W2_, &b2_,
                     &out_, &M_, &E_, &tl_ };
    hipError_t err = hipLaunchCooperativeKernel(
        reinterpret_cast<const void*>(fused_gemm_decode),
        dim3(FBLKS), dim3(256), args, 0, stream);

    if (err != hipSuccess) {
        // fallback: R4's separate launches
        node_gemm_v6<<<2 * tiles, 256, 0, stream>>>(
            z_src, z_dst, Wt, b1, Abuf, Bbuf, Nn, tiles);
        edge_decode_bf16<<<8192, 256, 0, stream>>>(
            Abuf, Bbuf, eidx, W2, b2, outp, E);
    }
}

// Round 7
// 295.113 us; speedup vs baseline: 2.2535x; 2.2535x over previous
//
#include <hip/hip_runtime.h>

#define HDIM 128

typedef __bf16 bf16_t;
typedef bf16_t bf16x8 __attribute__((ext_vector_type(8)));
typedef float  f32x4  __attribute__((ext_vector_type(4)));

__device__ __forceinline__ unsigned short f2bf_rne(float f) {
    unsigned int u = __float_as_uint(f);
    u += 0x7fffu + ((u >> 16) & 1u);   // round-to-nearest-even
    return (unsigned short)(u >> 16);
}
__device__ __forceinline__ unsigned int pk_bf2(float a, float b) {
    return (unsigned int)f2bf_rne(a) | ((unsigned int)f2bf_rne(b) << 16);
}

// W1 [2*128 k][128 n] fp32 -> Wt [2][n=128][k=128] bf16 (n-major, k-contiguous)
__global__ __launch_bounds__(256) void convert_w1(
    const float* __restrict__ W1, unsigned short* __restrict__ Wt)
{
    const int o = blockIdx.x * 256 + threadIdx.x;     // 0..32767
    const int g = o >> 14, rem = o & 16383, n = rem >> 7, k = rem & 127;
    Wt[o] = f2bf_rne(W1[g * 16384 + k * 128 + n]);
}

// C_bf16[M,128] = bf16(Z[M,128]) @ bf16(W[128,128]) (+ b1 if second half).
// v6 (best-total gemm variant, unchanged from R4): one 64-row tile per
// block; W staged once, XOR-swizzled chunks (T2); Z loads issued before
// the stage so HBM latency hides under it.
__global__ __launch_bounds__(256) void node_gemm_v6(
    const float* __restrict__ Zs, const float* __restrict__ Zd,
    const unsigned short* __restrict__ Wt, const float* __restrict__ b1,
    unsigned short* __restrict__ Abuf, unsigned short* __restrict__ Bbuf,
    int M, int tiles_per_half)
{
    __shared__ unsigned short wlds[128 * 128];   // 32 KB

    const bool second = (blockIdx.x >= tiles_per_half);
    const int tile = second ? (blockIdx.x - tiles_per_half) : blockIdx.x;
    const float* __restrict__ Z          = second ? Zd : Zs;
    const unsigned short* __restrict__ W = Wt + (second ? 128 * 128 : 0);
    unsigned short* __restrict__ C       = second ? Bbuf : Abuf;
    const int t    = threadIdx.x;
    const int lane = t & 63;
    const int wave = t >> 6;
    const int m    = lane & 15;     // Z row within wave's 16 / D col group
    const int quad = lane >> 4;

    // ---- issue Z loads first (HBM latency hides under W staging) ----
    const int r  = tile * 64 + wave * 16 + m;
    const int rc = (r < M) ? r : (M - 1);
    const float* zrow = Z + (size_t)rc * HDIM;
    float4 zv[4][2];
    #pragma unroll
    for (int ks = 0; ks < 4; ++ks) {
        zv[ks][0] = *reinterpret_cast<const float4*>(zrow + ks * 32 + quad * 8);
        zv[ks][1] = *reinterpret_cast<const float4*>(zrow + ks * 32 + quad * 8 + 4);
    }

    // ---- stage W (128 rows x 16 chunks of 16B), XOR-swizzled chunks ----
    #pragma unroll
    for (int j = 0; j < 8; ++j) {
        const int u = t + 256 * j;          // 0..2047
        const int n = u >> 4, cc = u & 15;
        const uint4 v = *reinterpret_cast<const uint4*>(W + n * 128 + cc * 8);
        *reinterpret_cast<uint4*>(wlds + n * 128 + (cc ^ (n & 7)) * 8) = v;
    }
    __syncthreads();

    // ---- pack Z to bf16 fragments ----
    union { unsigned int u[4]; bf16x8 h; } zf[4];
    #pragma unroll
    for (int ks = 0; ks < 4; ++ks) {
        zf[ks].u[0] = pk_bf2(zv[ks][0].x, zv[ks][0].y);
        zf[ks].u[1] = pk_bf2(zv[ks][0].z, zv[ks][0].w);
        zf[ks].u[2] = pk_bf2(zv[ks][1].x, zv[ks][1].y);
        zf[ks].u[3] = pk_bf2(zv[ks][1].z, zv[ks][1].w);
    }

    // ---- MFMA: acc[ct] += W[ct*16+m, ks*32..] * z ----
    f32x4 acc[8] = {};
    #pragma unroll
    for (int ks = 0; ks < 4; ++ks) {
        const int cidx = (ks * 4 + quad) ^ (m & 7);   // swizzled 16B-chunk
        #pragma unroll
        for (int ct = 0; ct < 8; ++ct) {
            const bf16x8 wf = *reinterpret_cast<const bf16x8*>(
                wlds + (ct * 16 + m) * 128 + cidx * 8);
            acc[ct] = __builtin_amdgcn_mfma_f32_16x16x32_bf16(
                wf, zf[ks].h, acc[ct], 0, 0, 0);
        }
    }

    // ---- epilogue: +bias, fp32->bf16, 8-B stores ----
    if (r < M) {
        unsigned short* crow = C + (size_t)r * HDIM;
        #pragma unroll
        for (int ct = 0; ct < 8; ++ct) {
            const int col = ct * 16 + quad * 4;
            float4 bv = make_float4(0.f, 0.f, 0.f, 0.f);
            if (second) bv = *reinterpret_cast<const float4*>(b1 + col);
            uint2 o;
            o.x = pk_bf2(acc[ct][0] + bv.x, acc[ct][1] + bv.y);
            o.y = pk_bf2(acc[ct][2] + bv.z, acc[ct][3] + bv.w);
            *reinterpret_cast<uint2*>(crow + col) = o;
        }
    }
}

// out[e] = relu(A[rows[e]] + B[cols[e]]) . W2 + b2, A/B bf16 (b1 folded in B).
// Body identical to the best-measured decode; two-pointer signature so the
// launcher can split the edge range (discrimination experiment: half-decode
// duration resolves the OH-vs-gemm budget ambiguity — see R6 notes).
__global__ __launch_bounds__(256) void edge_decode_bf16(
    const unsigned short* __restrict__ A, const unsigned short* __restrict__ Bm,
    const int* __restrict__ rows, const int* __restrict__ cols,
    const float* __restrict__ W2, const float* __restrict__ b2,
    float* __restrict__ out, int n)
{
    const int t   = threadIdx.x;
    const int sub = t & 15;
    const int grp = t >> 4;

    float w2r[8];
    #pragma unroll
    for (int i = 0; i < 8; ++i) w2r[i] = W2[sub * 8 + i];
    const float b2s = b2[0];

    const int stride = gridDim.x * 16;
    for (int e = blockIdx.x * 16 + grp; e < n; e += stride) {
        const int r = rows[e];
        const int c = cols[e];
        const uint4 av = *reinterpret_cast<const uint4*>(A  + (size_t)r * HDIM + sub * 8);
        const uint4 bv = *reinterpret_cast<const uint4*>(Bm + (size_t)c * HDIM + sub * 8);

        float s = 0.f;
        #pragma unroll
        for (int i = 0; i < 4; ++i) {
            const unsigned int ua = (&av.x)[i];
            const unsigned int ub = (&bv.x)[i];
            s += fmaxf(__uint_as_float(ua << 16)         + __uint_as_float(ub << 16),         0.f) * w2r[2 * i];
            s += fmaxf(__uint_as_float(ua & 0xffff0000u) + __uint_as_float(ub & 0xffff0000u), 0.f) * w2r[2 * i + 1];
        }
        s += __shfl_xor(s, 1);
        s += __shfl_xor(s, 2);
        s += __shfl_xor(s, 4);
        s += __shfl_xor(s, 8);
        if (sub == 0) out[e] = s + b2s;
    }
}

extern "C" void kernel_launch(void* const* d_in, const int* in_sizes, int n_in,
                              void* d_out, int out_size, void* d_ws, size_t ws_size,
                              hipStream_t stream)
{
    const float* z_src = (const float*)d_in[0];
    const float* z_dst = (const float*)d_in[1];
    const int*   eidx  = (const int*)d_in[2];
    const float* W1    = (const float*)d_in[3];
    const float* b1    = (const float*)d_in[4];
    const float* W2    = (const float*)d_in[5];
    const float* b2    = (const float*)d_in[6];
    float*       outp  = (float*)d_out;

    const int Nn = in_sizes[0] / HDIM;    // 100000
    const int E  = in_sizes[2] / 2;       // 2000000

    unsigned short* Abuf = (unsigned short*)d_ws;
    unsigned short* Bbuf = Abuf + (size_t)Nn * HDIM;
    unsigned short* Wt   = Bbuf + (size_t)Nn * HDIM;

    convert_w1<<<128, 256, 0, stream>>>(W1, Wt);

    const int tiles = (Nn + 63) >> 6;     // 1563
    node_gemm_v6<<<2 * tiles, 256, 0, stream>>>(
        z_src, z_dst, Wt, b1, Abuf, Bbuf, Nn, tiles);

    // 50/50 decode split (discrimination experiment; R3 showed halves <= 97):
    // World A (OH~100): halves ~69 each, total ~291, split is free.
    // World B (OH~50):  halves ~95, gemm_v6 tops the counter table at ~100.
    const int Eh = E / 2;
    edge_decode_bf16<<<8192, 256, 0, stream>>>(
        Abuf, Bbuf, eidx, eidx + E, W2, b2, outp, Eh);
    edge_decode_bf16<<<8192, 256, 0, stream>>>(
        Abuf, Bbuf, eidx + Eh, eidx + E + Eh, W2, b2, outp + Eh, E - Eh);
}